// Round 1
// baseline (2547.990 us; speedup 1.0000x reference)
//
#include <hip/hip_runtime.h>

#define B_ROWS 131072
#define NSTEP  65

typedef __attribute__((ext_vector_type(8))) short short8;
typedef __attribute__((ext_vector_type(4))) float floatx4;
typedef __attribute__((ext_vector_type(4))) unsigned int uintx4;

__device__ __forceinline__ unsigned short f2bf(float f) {
    unsigned int u = __builtin_bit_cast(unsigned int, f);
    u += 0x7FFFu + ((u >> 16) & 1u);   // RNE; inputs are finite
    return (unsigned short)(u >> 16);
}

// ---- pack W1 (65,63,256) fp32 -> bf16 frag order [stp][kc<2][n<256][32 k], k=63 zero-padded
__global__ __launch_bounds__(256) void pack_w1(const float* __restrict__ W1,
                                               unsigned short* __restrict__ out) {
    int t = blockIdx.x * 256 + threadIdx.x;            // 65*2*256 = 33280 threads
    int n = t & 255, kc = (t >> 8) & 1, stp = t >> 9;
    unsigned int wbuf[16];
#pragma unroll
    for (int e = 0; e < 16; ++e) {
        int k0 = kc * 32 + e * 2, k1 = k0 + 1;
        float v0 = (k0 < 63) ? W1[((size_t)stp * 63 + k0) * 256 + n] : 0.f;
        float v1 = (k1 < 63) ? W1[((size_t)stp * 63 + k1) * 256 + n] : 0.f;
        wbuf[e] = (unsigned)f2bf(v0) | ((unsigned)f2bf(v1) << 16);
    }
    uintx4* o = (uintx4*)out;
#pragma unroll
    for (int j = 0; j < 4; ++j) {
        uintx4 u = {wbuf[j*4+0], wbuf[j*4+1], wbuf[j*4+2], wbuf[j*4+3]};
        o[(size_t)t * 4 + j] = u;
    }
}

// ---- pack W2 (65,256,256) fp32 -> bf16 frag order [stp][kc<8][n<256][32 k]
__global__ __launch_bounds__(256) void pack_w2(const float* __restrict__ W2,
                                               unsigned short* __restrict__ out) {
    int t = blockIdx.x * 256 + threadIdx.x;            // 65*8*256 = 133120 threads
    int n = t & 255, kc = (t >> 8) & 7, stp = t >> 11;
    unsigned int wbuf[16];
#pragma unroll
    for (int e = 0; e < 16; ++e) {
        int k0 = kc * 32 + e * 2;
        float v0 = W2[((size_t)stp * 256 + k0) * 256 + n];
        float v1 = W2[((size_t)stp * 256 + k0 + 1) * 256 + n];
        wbuf[e] = (unsigned)f2bf(v0) | ((unsigned)f2bf(v1) << 16);
    }
    uintx4* o = (uintx4*)out;
#pragma unroll
    for (int j = 0; j < 4; ++j) {
        uintx4 u = {wbuf[j*4+0], wbuf[j*4+1], wbuf[j*4+2], wbuf[j*4+3]};
        o[(size_t)t * 4 + j] = u;
    }
}

// ---- zT[j][b] = x[b][j]  (tiled transpose)
__global__ __launch_bounds__(256) void init_z(const float* __restrict__ x,
                                              float* __restrict__ zT) {
    __shared__ float T[64][65];
    int tid = threadIdx.x;
    int b0 = blockIdx.x * 64;
    int r = tid >> 2, seg = tid & 3;
    const floatx4* xv = (const floatx4*)x;
#pragma unroll
    for (int m = 0; m < 4; ++m) {
        floatx4 v = xv[(size_t)(b0 + r) * 16 + seg * 4 + m];
        T[r][seg*16 + m*4 + 0] = v.x;
        T[r][seg*16 + m*4 + 1] = v.y;
        T[r][seg*16 + m*4 + 2] = v.z;
        T[r][seg*16 + m*4 + 3] = v.w;
    }
    __syncthreads();
    int j = tid >> 2;
    floatx4* zv = (floatx4*)zT;
#pragma unroll
    for (int m = 0; m < 4; ++m) {
        floatx4 v;
        v.x = T[seg*16 + m*4 + 0][j];
        v.y = T[seg*16 + m*4 + 1][j];
        v.z = T[seg*16 + m*4 + 2][j];
        v.w = T[seg*16 + m*4 + 3][j];
        zv[(size_t)j * (B_ROWS/4) + (b0 >> 2) + seg * 4 + m] = v;
    }
}

// ---- out[b][j] = exp(s[j]) * zT[j][b]
__global__ __launch_bounds__(256) void finalize(const float* __restrict__ zT,
                                                const float* __restrict__ s,
                                                float* __restrict__ out) {
    __shared__ float T[64][65];   // [b_local][j]
    int tid = threadIdx.x;
    int b0 = blockIdx.x * 64;
    int j = tid >> 2, seg = tid & 3;
    float sc = expf(s[j]);
    const floatx4* zv = (const floatx4*)zT;
#pragma unroll
    for (int m = 0; m < 4; ++m) {
        floatx4 v = zv[(size_t)j * (B_ROWS/4) + (b0 >> 2) + seg * 4 + m];
        T[seg*16 + m*4 + 0][j] = v.x * sc;
        T[seg*16 + m*4 + 1][j] = v.y * sc;
        T[seg*16 + m*4 + 2][j] = v.z * sc;
        T[seg*16 + m*4 + 3][j] = v.w * sc;
    }
    __syncthreads();
    int r = tid >> 2;
    floatx4* ov = (floatx4*)out;
#pragma unroll
    for (int m = 0; m < 4; ++m) {
        floatx4 v;
        v.x = T[r][seg*16 + m*4 + 0];
        v.y = T[r][seg*16 + m*4 + 1];
        v.z = T[r][seg*16 + m*4 + 2];
        v.w = T[r][seg*16 + m*4 + 3];
        ov[(size_t)(b0 + r) * 16 + seg * 4 + m] = v;
    }
}

// ---- one flow step, fully fused: permute -> L1 -> relu -> L2 -> relu -> dot w3 -> zT[i] += t
__global__ __launch_bounds__(256, 2) void step_kernel(
    float* __restrict__ zT,
    const unsigned short* __restrict__ Wb1p,
    const unsigned short* __restrict__ Wb2p,
    const float* __restrict__ b1g,
    const float* __restrict__ b2g,
    const float* __restrict__ w3g,
    const float* __restrict__ b3g,
    const int* __restrict__ idxg,
    int step)
{
    __shared__ uintx4 A1[64 * 8];    // [row][8 chunks of 8 bf16], chunk idx XOR (row&7)
    __shared__ uintx4 H1[64 * 32];   // [row][32 chunks of 8 bf16], chunk idx XOR (row&7)
    __shared__ float TR[4][64];

    const int tid  = threadIdx.x;
    const int w    = tid >> 6;
    const int lane = tid & 63;
    const int q    = lane >> 4;
    const int c    = lane & 15;
    const int c7   = c & 7;
    const int b0   = blockIdx.x << 6;
    const int i    = idxg[step];

    // ---- Phase 0: stage permuted z tile (bf16) into A1
    {
        int row = tid & 63;
        unsigned short hv[16];
#pragma unroll
        for (int kk = 0; kk < 16; ++kk) {
            int k  = w * 16 + kk;
            int kp = (k == i) ? 63 : k;            // column i slot gets old column 63
            float v = zT[(size_t)kp * B_ROWS + b0 + row];
            hv[kk] = f2bf(v);
        }
#pragma unroll
        for (int cc = 0; cc < 2; ++cc) {
            uintx4 u;
            u.x = (unsigned)hv[cc*8+0] | ((unsigned)hv[cc*8+1] << 16);
            u.y = (unsigned)hv[cc*8+2] | ((unsigned)hv[cc*8+3] << 16);
            u.z = (unsigned)hv[cc*8+4] | ((unsigned)hv[cc*8+5] << 16);
            u.w = (unsigned)hv[cc*8+6] | ((unsigned)hv[cc*8+7] << 16);
            A1[row * 8 + ((w * 2 + cc) ^ (row & 7))] = u;
        }
    }
    __syncthreads();

    const int n0 = w << 6;
    floatx4 acc[4][4];
#pragma unroll
    for (int rt = 0; rt < 4; ++rt)
#pragma unroll
        for (int ct = 0; ct < 4; ++ct) acc[rt][ct] = (floatx4){0.f, 0.f, 0.f, 0.f};

    // ---- Phase 1: h1 = relu(A1 @ W1 + b1), K = 64 (row 63 of W1 zero-padded)
    const uintx4* w1v = (const uintx4*)Wb1p;
#pragma unroll
    for (int kc = 0; kc < 2; ++kc) {
        short8 af[4], bf[4];
#pragma unroll
        for (int rt = 0; rt < 4; ++rt)
            af[rt] = __builtin_bit_cast(short8, A1[(rt * 16 + c) * 8 + ((kc * 4 + q) ^ c7)]);
#pragma unroll
        for (int ct = 0; ct < 4; ++ct)
            bf[ct] = __builtin_bit_cast(short8,
                w1v[((size_t)(step * 2 + kc) * 256 + n0 + ct * 16 + c) * 4 + q]);
#pragma unroll
        for (int rt = 0; rt < 4; ++rt)
#pragma unroll
            for (int ct = 0; ct < 4; ++ct)
                acc[rt][ct] = __builtin_amdgcn_mfma_f32_16x16x32_bf16(
                    af[rt], bf[ct], acc[rt][ct], 0, 0, 0);
    }

    // Phase-1 epilogue: bias + relu -> H1 (bf16, swizzled)
    unsigned short* H1s = (unsigned short*)H1;
#pragma unroll
    for (int ct = 0; ct < 4; ++ct) {
        int col = n0 + ct * 16 + c;
        float bias = b1g[step * 256 + col];
#pragma unroll
        for (int rt = 0; rt < 4; ++rt)
#pragma unroll
            for (int r = 0; r < 4; ++r) {
                int row = rt * 16 + q * 4 + r;
                float v = fmaxf(acc[rt][ct][r] + bias, 0.f);
                H1s[row * 256 + (((col >> 3) ^ (row & 7)) << 3) + (col & 7)] = f2bf(v);
            }
    }
    __syncthreads();

    // ---- Phase 2: h2 = relu(H1 @ W2 + b2), K = 256; never materialized
#pragma unroll
    for (int rt = 0; rt < 4; ++rt)
#pragma unroll
        for (int ct = 0; ct < 4; ++ct) acc[rt][ct] = (floatx4){0.f, 0.f, 0.f, 0.f};

    const uintx4* w2v = (const uintx4*)Wb2p;
#pragma unroll
    for (int kc = 0; kc < 8; ++kc) {
        short8 af[4], bf[4];
#pragma unroll
        for (int rt = 0; rt < 4; ++rt)
            af[rt] = __builtin_bit_cast(short8, H1[(rt * 16 + c) * 32 + ((kc * 4 + q) ^ c7)]);
#pragma unroll
        for (int ct = 0; ct < 4; ++ct)
            bf[ct] = __builtin_bit_cast(short8,
                w2v[((size_t)(step * 8 + kc) * 256 + n0 + ct * 16 + c) * 4 + q]);
#pragma unroll
        for (int rt = 0; rt < 4; ++rt)
#pragma unroll
            for (int ct = 0; ct < 4; ++ct)
                acc[rt][ct] = __builtin_amdgcn_mfma_f32_16x16x32_bf16(
                    af[rt], bf[ct], acc[rt][ct], 0, 0, 0);
    }

    // ---- Epilogue: t = relu(h2 + b2) . w3 + b3 ; zT[i][b] += t
    float b2v[4], w3v[4];
#pragma unroll
    for (int ct = 0; ct < 4; ++ct) {
        int col = n0 + ct * 16 + c;
        b2v[ct] = b2g[step * 256 + col];
        w3v[ct] = w3g[step * 256 + col];
    }
#pragma unroll
    for (int rt = 0; rt < 4; ++rt) {
#pragma unroll
        for (int r = 0; r < 4; ++r) {
            float p = 0.f;
#pragma unroll
            for (int ct = 0; ct < 4; ++ct)
                p += fmaxf(acc[rt][ct][r] + b2v[ct], 0.f) * w3v[ct];
            p += __shfl_xor(p, 1, 64);
            p += __shfl_xor(p, 2, 64);
            p += __shfl_xor(p, 4, 64);
            p += __shfl_xor(p, 8, 64);
            if (c == 0) TR[w][rt * 16 + q * 4 + r] = p;
        }
    }
    __syncthreads();
    if (tid < 64) {
        float t = TR[0][tid] + TR[1][tid] + TR[2][tid] + TR[3][tid] + b3g[step];
        zT[(size_t)i * B_ROWS + b0 + tid] += t;
    }
}

extern "C" void kernel_launch(void* const* d_in, const int* in_sizes, int n_in,
                              void* d_out, int out_size, void* d_ws, size_t ws_size,
                              hipStream_t stream) {
    const float* x  = (const float*)d_in[0];
    const float* s  = (const float*)d_in[1];
    const float* W1 = (const float*)d_in[2];
    const float* b1 = (const float*)d_in[3];
    const float* W2 = (const float*)d_in[4];
    const float* b2 = (const float*)d_in[5];
    const float* W3 = (const float*)d_in[6];
    const float* b3 = (const float*)d_in[7];
    const int* idx  = (const int*)d_in[8];
    float* out = (float*)d_out;

    char* ws = (char*)d_ws;
    const size_t ZT_BYTES  = (size_t)64 * B_ROWS * 4;          // 33,554,432
    const size_t W1P_BYTES = (size_t)NSTEP * 2 * 256 * 32 * 2; //  2,129,920
    float* zT            = (float*)ws;
    unsigned short* Wb1p = (unsigned short*)(ws + ZT_BYTES);
    unsigned short* Wb2p = (unsigned short*)(ws + ZT_BYTES + W1P_BYTES);

    pack_w1<<<130, 256, 0, stream>>>(W1, Wb1p);
    pack_w2<<<520, 256, 0, stream>>>(W2, Wb2p);
    init_z<<<B_ROWS / 64, 256, 0, stream>>>(x, zT);
    for (int stp = 0; stp < NSTEP; ++stp)
        step_kernel<<<B_ROWS / 64, 256, 0, stream>>>(zT, Wb1p, Wb2p, b1, b2, W3, b3, idx, stp);
    finalize<<<B_ROWS / 64, 256, 0, stream>>>(zT, s, out);
}